// Round 1
// baseline (8103.555 us; speedup 1.0000x reference)
//
#include <hip/hip_runtime.h>

typedef unsigned short u16;
typedef unsigned int u32;
typedef __bf16 bf16x8 __attribute__((ext_vector_type(8)));
typedef float f32x4 __attribute__((ext_vector_type(4)));
typedef u16 u16x4 __attribute__((ext_vector_type(4)));
typedef u16 u16x8 __attribute__((ext_vector_type(8)));

// Problem constants: B=256, T=512, H=1024
#define HDIM 1024
#define BATCH 256
#define TSTEPS 512
#define BT (BATCH * TSTEPS)   // 131072 rows of x

// ---------- bf16 helpers (RNE, bit-level; no NaNs in this data) ----------
__device__ __forceinline__ u16 f2bf(float f) {
  union { float f; u32 u; } v; v.f = f;
  u32 r = v.u + 0x7FFFu + ((v.u >> 16) & 1u);
  return (u16)(r >> 16);
}
__device__ __forceinline__ float bf2f(u16 u) {
  union { u32 u; float f; } v; v.u = ((u32)u) << 16;
  return v.f;
}

// ---------- async global->LDS, 16B per lane, wave-uniform LDS base ----------
__device__ __forceinline__ void gload_lds16(const void* g, void* l) {
  __builtin_amdgcn_global_load_lds(
      (const __attribute__((address_space(1))) unsigned int*)g,
      (__attribute__((address_space(3))) unsigned int*)l, 16, 0, 0);
}

// =====================================================================
// Kernel 1: pack weights to bf16 (Wcat=[Wz;Wh], Ucat=[Uz;Uh], N x K) + h init
// =====================================================================
__global__ __launch_bounds__(256) void pack_kernel(
    const float* __restrict__ Wz, const float* __restrict__ Uz,
    const float* __restrict__ Wh, const float* __restrict__ Uh,
    const float* __restrict__ ht,
    u16* __restrict__ Wcat, u16* __restrict__ Ucat,
    float* __restrict__ hf0, u16* __restrict__ hb0)
{
  const long M = 1L << 20;  // 1024*1024
  long e = ((long)blockIdx.x * 256 + threadIdx.x) * 4;
  const float* src;
  u16* dst;
  if (e < M)            { src = Wz + e;        dst = Wcat + e; }
  else if (e < 2 * M)   { src = Wh + (e - M);  dst = Wcat + e; }
  else if (e < 3 * M)   { src = Uz + (e - 2*M); dst = Ucat + (e - 2*M); }
  else if (e < 4 * M)   { src = Uh + (e - 3*M); dst = Ucat + (e - 2*M); }
  else {
    long j = e - 4 * M;  // [0, 256*1024)
    float4 v = *(const float4*)(ht + j);
    *(float4*)(hf0 + j) = v;
    u16x4 o = { f2bf(v.x), f2bf(v.y), f2bf(v.z), f2bf(v.w) };
    *(u16x4*)(hb0 + j) = o;
    return;
  }
  float4 v = *(const float4*)src;
  u16x4 o = { f2bf(v.x), f2bf(v.y), f2bf(v.z), f2bf(v.w) };
  *(u16x4*)dst = o;
}

// =====================================================================
// Kernel 2: phase-1 GEMM  xzh[t][b][n] = sum_k x[b][t][k] * Wcat[n][k]
// 128x128 tile, BK=64, B via global_load_lds, A reg-staged fp32->bf16.
// =====================================================================
__global__ __launch_bounds__(256) void gemm_xw(
    const float* __restrict__ x, const u16* __restrict__ Wcat,
    u16* __restrict__ xzh)
{
  __shared__ u16 As[128 * 64];  // 16KB [row][k]
  __shared__ u16 Bs[128 * 64];  // 16KB [n][k]

  const int NWG = (BT / 128) * (2048 / 128);  // 1024*16 = 16384
  int bid = blockIdx.x;
  int swz = (bid & 7) * (NWG / 8) + (bid >> 3);  // XCD-contiguous chunks
  int tm = swz >> 4;   // m-tile [0,1024)
  int tn = swz & 15;   // n-tile [0,16)   (n fastest -> A-panel reuse in L2)
  long m0 = (long)tm * 128;
  int n0 = tn * 128;

  int tid = threadIdx.x;
  int w = tid >> 6, l = tid & 63;
  int wr = (w >> 1) * 64;  // wave row offset in tile
  int wc = (w & 1) * 64;   // wave col offset

  f32x4 acc[4][4] = {};

  const int arow = tid >> 3;        // 0..31
  const int acol = (tid & 7) * 8;   // 0..56
  const int brow = l >> 3;          // 0..7
  const int bcol = (l & 7) * 8;

  for (int kc = 0; kc < 16; ++kc) {
    int k0 = kc * 64;
    // B: 16 x 1KB async issues (4 per wave)
#pragma unroll
    for (int j = 0; j < 4; ++j) {
      int r = (w * 4 + j) * 8 + brow;
      gload_lds16(Wcat + (((long)(n0 + r)) << 10) + k0 + bcol,
                  &Bs[(w * 4 + j) * 512]);
    }
    // A: 32 fp32 per thread -> bf16 -> LDS (stride-16B writes, conflict-free)
    float4 av[4][2];
#pragma unroll
    for (int s = 0; s < 4; ++s) {
      const float* src = x + ((m0 + arow + s * 32) << 10) + k0 + acol;
      av[s][0] = *(const float4*)src;
      av[s][1] = *(const float4*)(src + 4);
    }
#pragma unroll
    for (int s = 0; s < 4; ++s) {
      u16x8 o = { f2bf(av[s][0].x), f2bf(av[s][0].y), f2bf(av[s][0].z), f2bf(av[s][0].w),
                  f2bf(av[s][1].x), f2bf(av[s][1].y), f2bf(av[s][1].z), f2bf(av[s][1].w) };
      *(u16x8*)(As + tid * 8 + s * 2048) = o;
    }
    __syncthreads();  // drains vmcnt (B stage) + lgkm (A writes)
#pragma unroll
    for (int kk = 0; kk < 2; ++kk) {
      int kb = kk * 32 + (l >> 4) * 8;
      int rr = l & 15;
      bf16x8 af[4], bfr[4];
#pragma unroll
      for (int i = 0; i < 4; ++i)
        af[i] = *(const bf16x8*)(As + (wr + i * 16 + rr) * 64 + kb);
#pragma unroll
      for (int j = 0; j < 4; ++j)
        bfr[j] = *(const bf16x8*)(Bs + (wc + j * 16 + rr) * 64 + kb);
#pragma unroll
      for (int i = 0; i < 4; ++i)
#pragma unroll
        for (int j = 0; j < 4; ++j)
          acc[i][j] = __builtin_amdgcn_mfma_f32_16x16x32_bf16(af[i], bfr[j], acc[i][j], 0, 0, 0);
    }
    __syncthreads();
  }

  // Epilogue: C row m=(b*512+t) -> stored row (t*256+b), bf16
  int rq = (l >> 4) * 4;
  int rc = l & 15;
#pragma unroll
  for (int i = 0; i < 4; ++i) {
#pragma unroll
    for (int r = 0; r < 4; ++r) {
      long m = m0 + wr + i * 16 + rq + r;
      int b = (int)(m >> 9);
      int t = (int)(m & 511);
      u16* dst = xzh + (((long)t * 256 + b) << 11);
#pragma unroll
      for (int j = 0; j < 4; ++j)
        dst[n0 + wc + j * 16 + rc] = f2bf(acc[i][j][r]);
    }
  }
}

// =====================================================================
// Kernel 3: one GRU step.  Per block: 32 b-rows x 32 o-cols, BOTH gates.
// z = sigmoid(xz + h@Uz^T); h~ = tanh(xh + h@Uh^T); h' = z*h + (1-z)*h~
// Double-buffered BK=64 chunks with counted vmcnt(3) prefetch.
// =====================================================================
__global__ __launch_bounds__(256) void gru_step(
    const u16* __restrict__ Ucat, const u16* __restrict__ xzh_t,
    const u16* __restrict__ hbc, const float* __restrict__ hfc,
    u16* __restrict__ hbn, float* __restrict__ hfn)
{
  __shared__ u16 As[2][32 * 64];   // h chunk       4KB x2
  __shared__ u16 Bzs[2][32 * 64];  // Uz rows chunk 4KB x2
  __shared__ u16 Bhs[2][32 * 64];  // Uh rows chunk 4KB x2

  int bid = blockIdx.x;
  int swz = (bid & 7) * 32 + (bid >> 3);  // 256 blocks, bijective
  int b0 = (swz >> 5) * 32;  // b-tile
  int o0 = (swz & 31) * 32;  // o-tile

  int tid = threadIdx.x;
  int w = tid >> 6, l = tid & 63;
  int wr = (w >> 1) * 16;  // wave b offset
  int wc = (w & 1) * 16;   // wave o offset

  f32x4 accZ = {0.f, 0.f, 0.f, 0.f};
  f32x4 accH = {0.f, 0.f, 0.f, 0.f};

  const int srow = l >> 3;         // 0..7
  const int scol = (l & 7) * 8;    // 0..56

#define STAGE(kc, buf) do {                                                          \
    int k0_ = (kc) * 64;                                                             \
    gload_lds16(hbc  + (((long)(b0 + w * 8 + srow)) << 10) + k0_ + scol,             \
                &As[buf][w * 512]);                                                  \
    gload_lds16(Ucat + (((long)(o0 + w * 8 + srow)) << 10) + k0_ + scol,             \
                &Bzs[buf][w * 512]);                                                 \
    gload_lds16(Ucat + (((long)(1024 + o0 + w * 8 + srow)) << 10) + k0_ + scol,      \
                &Bhs[buf][w * 512]);                                                 \
  } while (0)

  STAGE(0, 0);
#pragma unroll
  for (int kc = 0; kc < 16; ++kc) {
    int buf = kc & 1;
    if (kc < 15) {
      STAGE(kc + 1, buf ^ 1);
      asm volatile("s_waitcnt vmcnt(3)" ::: "memory");  // cur chunk landed; next 3 in flight
    } else {
      asm volatile("s_waitcnt vmcnt(0)" ::: "memory");
    }
    asm volatile("s_barrier" ::: "memory");
#pragma unroll
    for (int kk = 0; kk < 2; ++kk) {
      int kb = kk * 32 + (l >> 4) * 8;
      int rr = l & 15;
      bf16x8 a  = *(const bf16x8*)(&As[buf][(wr + rr) * 64 + kb]);
      bf16x8 bz = *(const bf16x8*)(&Bzs[buf][(wc + rr) * 64 + kb]);
      bf16x8 bh = *(const bf16x8*)(&Bhs[buf][(wc + rr) * 64 + kb]);
      accZ = __builtin_amdgcn_mfma_f32_16x16x32_bf16(a, bz, accZ, 0, 0, 0);
      accH = __builtin_amdgcn_mfma_f32_16x16x32_bf16(a, bh, accH, 0, 0, 0);
    }
    asm volatile("s_barrier" ::: "memory");  // protect buf before re-stage
  }
#undef STAGE

  // Epilogue in fp32
  int rq = (l >> 4) * 4;
  int rc = l & 15;
  int col = o0 + wc + rc;
#pragma unroll
  for (int r = 0; r < 4; ++r) {
    int bq = b0 + wr + rq + r;
    float xz = bf2f(xzh_t[(((long)bq) << 11) + col]);
    float xh = bf2f(xzh_t[(((long)bq) << 11) + 1024 + col]);
    float hold = hfc[(((long)bq) << 10) + col];
    float zp = accZ[r] + xz;
    float hp = accH[r] + xh;
    float z = 1.f / (1.f + __expf(-zp));
    float hh = tanhf(hp);
    float hnew = z * hold + (1.f - z) * hh;
    hfn[(((long)bq) << 10) + col] = hnew;
    hbn[(((long)bq) << 10) + col] = f2bf(hnew);
  }
}

// =====================================================================
// Kernel 4: h_final -> d_out (duplicated: reference returns a 2-tuple)
// =====================================================================
__global__ __launch_bounds__(256) void copy_out(const float* __restrict__ hf,
                                                float* __restrict__ out)
{
  int i = blockIdx.x * 256 + threadIdx.x;  // 65536 float4s
  float4 v = ((const float4*)hf)[i];
  ((float4*)out)[i] = v;
  ((float4*)(out + BATCH * HDIM))[i] = v;
}

// =====================================================================
extern "C" void kernel_launch(void* const* d_in, const int* in_sizes, int n_in,
                              void* d_out, int out_size, void* d_ws, size_t ws_size,
                              hipStream_t stream)
{
  const float* x  = (const float*)d_in[0];
  const float* ht = (const float*)d_in[1];
  const float* Wz = (const float*)d_in[2];
  const float* Uz = (const float*)d_in[3];
  // d_in[4]=Wr, d_in[5]=Ur are dead in the reference
  const float* Wh = (const float*)d_in[6];
  const float* Uh = (const float*)d_in[7];

  char* ws = (char*)d_ws;
  // layout: xzh 512MB | Wcat 4MB | Ucat 4MB | hf[2] 2MB | hb[2] 1MB  (~523MB)
  u16*   xzh  = (u16*)ws;
  u16*   Wcat = (u16*)(ws + 536870912L);
  u16*   Ucat = (u16*)(ws + 536870912L + 4194304L);
  float* hf   = (float*)(ws + 536870912L + 8388608L);
  u16*   hb   = (u16*)(ws + 536870912L + 8388608L + 2097152L);

  pack_kernel<<<4352, 256, 0, stream>>>(Wz, Uz, Wh, Uh, ht, Wcat, Ucat, hf, hb);
  gemm_xw<<<16384, 256, 0, stream>>>(x, Wcat, xzh);

  const long HB = (long)BATCH * HDIM;  // 262144
  for (int t = 0; t < TSTEPS; ++t) {
    int cur = t & 1, nxt = cur ^ 1;
    gru_step<<<256, 256, 0, stream>>>(Ucat, xzh + (long)t * BATCH * 2048,
                                      hb + cur * HB, hf + cur * HB,
                                      hb + nxt * HB, hf + nxt * HB);
  }
  // final h lives in parity (512 & 1) == 0
  copy_out<<<256, 256, 0, stream>>>(hf, (float*)d_out);
}